// Round 1
// baseline (139.177 us; speedup 1.0000x reference)
//
#include <hip/hip_runtime.h>
#include <math.h>

// Problem constants (from reference)
#define TT 10
#define SS 10
#define RR 2000
#define KK 100
#define OO 500
#define PP (TT*SS*RR)        // 200000 particles
#define NTILES (PP/16)       // 12500 M-tiles of 16 particles
#define NT 7                 // 7 N-tiles of 16 cols -> 112 padded assemblages
#define NWAVES_TOTAL 4096    // 256 blocks * 16 waves
#define EPSF 1e-6f

typedef float        f32x4  __attribute__((ext_vector_type(4)));
typedef unsigned int u32x4  __attribute__((ext_vector_type(4)));
typedef __bf16       bf16x8 __attribute__((ext_vector_type(8)));

union BFU { bf16x8 v; u32x4 q; };

// XOR swizzle: spreads the 16B chunks of a row across bank-quads so that
// B-frag ds_read_b128 (lanes 0..15 read rows nt*16+lo at the same k-offset,
// i.e. stride 1024B) hits the b128 bank floor instead of a 4x-serialized set.
__device__ __forceinline__ int swz(int row, int byteInRow) {
    return row * 1024 + (byteInRow ^ ((row & 7) << 4));
}

// ---------------------------------------------------------------------------
// Prep: theta = softmax(theta_params) -> out[1..50001); beta copy -> out[50001..);
// out[0] = 0 (accumulator for -loglik).
// ---------------------------------------------------------------------------
__global__ __launch_bounds__(64) void mcspace_prep(
    const float* __restrict__ theta_params,
    const float* __restrict__ beta,
    float* __restrict__ out)
{
    const int b  = blockIdx.x;
    const int ln = threadIdx.x;   // 64 lanes, one wave
    if (b < KK) {
        const float* tp = theta_params + b * OO;
        float x[8];
        #pragma unroll
        for (int j = 0; j < 8; ++j) {
            int o = ln + 64 * j;
            x[j] = (o < OO) ? tp[o] : -INFINITY;
        }
        float mx = x[0];
        #pragma unroll
        for (int j = 1; j < 8; ++j) mx = fmaxf(mx, x[j]);
        #pragma unroll
        for (int w = 1; w < 64; w <<= 1) mx = fmaxf(mx, __shfl_xor(mx, w));
        float e[8], sm = 0.f;
        #pragma unroll
        for (int j = 0; j < 8; ++j) { e[j] = __expf(x[j] - mx); sm += e[j]; }
        #pragma unroll
        for (int w = 1; w < 64; w <<= 1) sm += __shfl_xor(sm, w);
        const float inv = 1.f / sm;
        float* to = out + 1 + b * OO;
        #pragma unroll
        for (int j = 0; j < 8; ++j) {
            int o = ln + 64 * j;
            if (o < OO) to[o] = e[j] * inv;
        }
    } else {
        int idx = (b - KK) * 64 + ln;
        if (idx < KK * TT * SS) out[1 + KK * OO + idx] = beta[idx];
        if (b == KK && ln == 0) out[0] = 0.f;
    }
}

// ---------------------------------------------------------------------------
// Main: rlog = counts @ logtheta^T via bf16 MFMA, then beta-weighted
// logsumexp over assemblages, accumulate -sum into out[0].
// ---------------------------------------------------------------------------
__global__ __launch_bounds__(1024) void mcspace_main(
    const float* __restrict__ counts,
    const float* __restrict__ theta_params,
    const float* __restrict__ beta,
    float* __restrict__ out)
{
    __shared__ u32x4 ldsB[7168];   // logtheta bf16 [112][512], swizzled rows (112 KB)
    __shared__ float red[16];
    char* ldsBytes = (char*)&ldsB[0];

    const int tid = threadIdx.x;
    const int wv  = tid >> 6;     // wave id 0..15
    const int ln  = tid & 63;
    const int lo  = ln & 15;
    const int g   = ln >> 4;

    // ---- build logtheta bf16 [112][512] in LDS (each wave does 7 rows) ----
    for (int it = 0; it < 7; ++it) {
        const int row = wv + 16 * it;          // 0..111 (bijective)
        BFU w8; w8.q = (u32x4){0u, 0u, 0u, 0u};
        if (row < KK) {
            const float* tp = theta_params + row * OO;
            float x[8];
            #pragma unroll
            for (int j = 0; j < 8; ++j) {
                int o = ln * 8 + j;
                x[j] = (o < OO) ? tp[o] : -INFINITY;
            }
            float mx = x[0];
            #pragma unroll
            for (int j = 1; j < 8; ++j) mx = fmaxf(mx, x[j]);
            #pragma unroll
            for (int w = 1; w < 64; w <<= 1) mx = fmaxf(mx, __shfl_xor(mx, w));
            float e[8], sm = 0.f;
            #pragma unroll
            for (int j = 0; j < 8; ++j) { e[j] = __expf(x[j] - mx); sm += e[j]; }
            #pragma unroll
            for (int w = 1; w < 64; w <<= 1) sm += __shfl_xor(sm, w);
            const float inv = 1.f / sm;
            #pragma unroll
            for (int j = 0; j < 8; ++j)
                w8.v[j] = (__bf16)__logf(e[j] * inv + EPSF);  // log(theta + EPS)
        }
        *(u32x4*)(ldsBytes + swz(row, ln * 16)) = w8.q;
    }
    __syncthreads();

    float wacc = 0.f;
    const int gw = blockIdx.x * 16 + wv;     // global wave id, 0..4095
    const int kb = g * 8;                    // k base within 32-step for this lane group

    for (int tile = gw; tile < NTILES; tile += NWAVES_TOTAL) {
        const int pbase = tile * 16;
        const int ts = pbase / RR;           // t*S + s (R divisible by 16)
        const float* rp = counts + (long)(pbase + lo) * OO;

        // beta for this tile's (t,s): lane lo owns column j = nt*16+lo
        float bet[NT];
        #pragma unroll
        for (int nt = 0; nt < NT; ++nt) {
            int j = nt * 16 + lo;
            bet[nt] = (j < KK) ? beta[j * (TT * SS) + ts] : 0.f;
        }

        f32x4 acc[NT];
        #pragma unroll
        for (int nt = 0; nt < NT; ++nt) acc[nt] = (f32x4){0.f, 0.f, 0.f, 0.f};

        // 15 full K-steps of 32 (k = 0..479)
        #pragma unroll 3
        for (int ko = 0; ko < 15; ++ko) {
            f32x4 a0 = *(const f32x4*)(rp + ko * 32 + kb);
            f32x4 a1 = *(const f32x4*)(rp + ko * 32 + kb + 4);
            BFU a;
            #pragma unroll
            for (int j = 0; j < 4; ++j) {
                a.v[j]     = (__bf16)a0[j];
                a.v[4 + j] = (__bf16)a1[j];
            }
            const int bb = ko * 64 + g * 16;
            #pragma unroll
            for (int nt = 0; nt < NT; ++nt) {
                BFU bv;
                bv.q = *(const u32x4*)(ldsBytes + swz(nt * 16 + lo, bb));
                acc[nt] = __builtin_amdgcn_mfma_f32_16x16x32_bf16(a.v, bv.v, acc[nt], 0, 0, 0);
            }
        }
        // remainder K-step: k = 480..511, only k < 500 valid (guard avoids OOB)
        {
            BFU a;
            #pragma unroll
            for (int j = 0; j < 8; ++j) {
                int k = 480 + kb + j;
                a.v[j] = (__bf16)((k < OO) ? rp[k] : 0.f);
            }
            const int bb = 15 * 64 + g * 16;
            #pragma unroll
            for (int nt = 0; nt < NT; ++nt) {
                BFU bv;
                bv.q = *(const u32x4*)(ldsBytes + swz(nt * 16 + lo, bb));
                acc[nt] = __builtin_amdgcn_mfma_f32_16x16x32_bf16(a.v, bv.v, acc[nt], 0, 0, 0);
            }
        }

        // ---- beta-weighted logsumexp over assemblages ----
        // D layout: lane holds rows i = 4*g + r (r=0..3) at column j = nt*16+lo.
        float mrow[4] = {-INFINITY, -INFINITY, -INFINITY, -INFINITY};
        #pragma unroll
        for (int nt = 0; nt < NT; ++nt) {
            const bool valid = (nt * 16 + lo) < KK;
            #pragma unroll
            for (int r = 0; r < 4; ++r) {
                float v = valid ? acc[nt][r] : -INFINITY;
                mrow[r] = fmaxf(mrow[r], v);
            }
        }
        #pragma unroll
        for (int w = 1; w < 16; w <<= 1) {
            #pragma unroll
            for (int r = 0; r < 4; ++r)
                mrow[r] = fmaxf(mrow[r], __shfl_xor(mrow[r], w));
        }
        float srow[4] = {0.f, 0.f, 0.f, 0.f};
        #pragma unroll
        for (int nt = 0; nt < NT; ++nt) {
            const bool valid = (nt * 16 + lo) < KK;
            #pragma unroll
            for (int r = 0; r < 4; ++r) {
                float v = valid ? (acc[nt][r] - mrow[r]) : -INFINITY;
                srow[r] += bet[nt] * __expf(v);
            }
        }
        #pragma unroll
        for (int w = 1; w < 16; w <<= 1) {
            #pragma unroll
            for (int r = 0; r < 4; ++r)
                srow[r] += __shfl_xor(srow[r], w);
        }
        if (lo == 0) {
            #pragma unroll
            for (int r = 0; r < 4; ++r)
                wacc += mrow[r] + __logf(srow[r] + EPSF);
        }
    }

    // block reduction (deterministic), then one atomic per block
    #pragma unroll
    for (int w = 1; w < 64; w <<= 1) wacc += __shfl_xor(wacc, w);
    if (ln == 0) red[wv] = wacc;
    __syncthreads();
    if (tid == 0) {
        float s = 0.f;
        #pragma unroll
        for (int i = 0; i < 16; ++i) s += red[i];
        atomicAdd(out, -s);   // elbo_loss = -loglik
    }
}

extern "C" void kernel_launch(void* const* d_in, const int* in_sizes, int n_in,
                              void* d_out, int out_size, void* d_ws, size_t ws_size,
                              hipStream_t stream)
{
    (void)in_sizes; (void)n_in; (void)d_ws; (void)ws_size; (void)out_size;
    const float* counts       = (const float*)d_in[0];
    const float* theta_params = (const float*)d_in[1];
    const float* beta         = (const float*)d_in[2];
    float* out = (float*)d_out;

    // prep: 100 softmax rows + 157 beta-copy blocks (one wave each)
    mcspace_prep<<<dim3(KK + (KK * TT * SS + 63) / 64), dim3(64), 0, stream>>>(
        theta_params, beta, out);
    // main: 256 blocks (1/CU) x 16 waves, wave-strided over 12500 particle tiles
    mcspace_main<<<dim3(256), dim3(1024), 0, stream>>>(
        counts, theta_params, beta, out);
}